// Round 6
// baseline (148.841 us; speedup 1.0000x reference)
//
#include <hip/hip_runtime.h>
#include <math.h>

// Problem constants (from reference)
#define BB 16
#define NN 65536
#define DD 8
#define OUT_SIZE 4096
#define IN_SIZE 4096

#define BLOCKS_PER_B 32
#define NC (NN / BLOCKS_PER_B)            // 2048 tuples per block
#define BLOCK_THREADS 1024                // 16 waves/block, 2 blocks/CU
#define TUPLES_PER_ITER (BLOCK_THREADS/4) // 256 tuples/iter (1 tuple per 4-lane quad)
#define NITER (NC / TUPLES_PER_ITER)      // 8 iterations

// y[b,o] = bias[o]  (output is re-poisoned before every timed launch)
__global__ void init_out(const float* __restrict__ bias, float* __restrict__ y) {
    int i = blockIdx.x * blockDim.x + threadIdx.x;     // 0 .. B*OUT_SIZE-1
    y[i] = bias[i & (OUT_SIZE - 1)];
}

__global__ __launch_bounds__(BLOCK_THREADS, 8)
void hyper_scatter(const float* __restrict__ x,
                   const float* __restrict__ means,
                   const float* __restrict__ sigmas,
                   const float* __restrict__ values,
                   const float* __restrict__ noise,
                   float* __restrict__ y) {
    __shared__ float ys[OUT_SIZE];   // per-(b,chunk) partial output, 16 KB

    const int b     = blockIdx.x / BLOCKS_PER_B;
    const int chunk = blockIdx.x % BLOCKS_PER_B;
    const int tid   = threadIdx.x;
    const int q     = tid & 3;               // lane position within quad
    const float* xb = x + (size_t)b * IN_SIZE;

    // zero partial accumulator (1024 threads cover all 1024 float4s)
    ((float4*)ys)[tid] = make_float4(0.f, 0.f, 0.f, 0.f);
    __syncthreads();

    const int n0 = chunk * NC;
    const size_t tb = (size_t)b * NN + n0;   // first tuple of this block

    // ---- software-pipelined loop: prefetch next iter's inputs ----
    // iteration `it`: quad (tid>>2) handles tuple tb + it*256 + (tid>>2);
    // lane loads float4 #q of that tuple => global float4 index
    // (tb + it*256)*4 + tid  -> PERFECTLY COALESCED (1 KB/wave/instr).
    float4 nz   = ((const float4*)noise)[(tb + 0) * 4 + tid];
    float2 mean = ((const float2*)means)[tb + (tid >> 2)];
    float  sigma = sigmas[tb + (tid >> 2)];
    float  value = values[tb + (tid >> 2)];

    for (int it = 0; it < NITER; ++it) {
        float4 nz_n; float2 mean_n; float sigma_n, value_n;
        if (it + 1 < NITER) {
            const size_t tn = tb + (size_t)(it + 1) * TUPLES_PER_ITER;
            nz_n    = ((const float4*)noise)[tn * 4 + tid];
            mean_n  = ((const float2*)means)[tn + (tid >> 2)];
            sigma_n = sigmas[tn + (tid >> 2)];
            value_n = values[tn + (tid >> 2)];
        }

        // ---- two samples per lane (samples 2q and 2q+1 of the tuple) ----
        const float neg_inv_2s2 = -0.5f / (sigma * sigma);
        // EXACT sample rounding: mul-then-add, no FMA contraction, so
        // rintf() flips the same half-integer cases as np.round.
        float sA0 = __fadd_rn(__fmul_rn(nz.x, sigma), mean.x);
        float sA1 = __fadd_rn(__fmul_rn(nz.y, sigma), mean.y);
        float sB0 = __fadd_rn(__fmul_rn(nz.z, sigma), mean.x);
        float sB1 = __fadd_rn(__fmul_rn(nz.w, sigma), mean.y);
        float dA0 = sA0 - mean.x, dA1 = sA1 - mean.y;
        float dB0 = sB0 - mean.x, dB1 = sB1 - mean.y;
        float pA = __expf((dA0 * dA0 + dA1 * dA1) * neg_inv_2s2);
        float pB = __expf((dB0 * dB0 + dB1 * dB1) * neg_inv_2s2);
        int oiA = (int)fminf(fmaxf(rintf(sA0), 0.f), (float)(OUT_SIZE - 1));
        int iiA = (int)fminf(fmaxf(rintf(sA1), 0.f), (float)(IN_SIZE - 1));
        int oiB = (int)fminf(fmaxf(rintf(sB0), 0.f), (float)(OUT_SIZE - 1));
        int iiB = (int)fminf(fmaxf(rintf(sB1), 0.f), (float)(IN_SIZE - 1));
        int kA = (oiA << 12) | iiA;
        int kB = (oiB << 12) | iiB;

        // psum over the tuple's 8 samples: quad butterfly (VALU only)
        float pAB = pA + pB;
        float t1  = pAB + __shfl_xor(pAB, 1, 4);
        float psum = t1 + __shfl_xor(t1, 2, 4);
        const float wscale = value / psum;

        // ---- quad-level dedupe: gather all 8 (key,p) via shuffles ----
        int   kA1 = __shfl_xor(kA, 1, 4), kB1 = __shfl_xor(kB, 1, 4);
        float pA1 = __shfl_xor(pA, 1, 4), pB1 = __shfl_xor(pB, 1, 4);
        int   kA2 = __shfl_xor(kA, 2, 4), kB2 = __shfl_xor(kB, 2, 4);
        float pA2 = __shfl_xor(pA, 2, 4), pB2 = __shfl_xor(pB, 2, 4);
        int   kA3 = __shfl_xor(kA, 3, 4), kB3 = __shfl_xor(kB, 3, 4);
        float pA3 = __shfl_xor(pA, 3, 4), pB3 = __shfl_xor(pB, 3, 4);
        // global slot order s = 2*quadlane + {0,1}; partner via mask m sits
        // at quadlane q^m: "earlier" iff (q^m) < q.
        bool e1 = (q ^ 1) < q, e2 = (q ^ 2) < q, e3 = (q ^ 3) < q;

        // slot A (s = 2q): dead if any earlier slot has same key;
        // else accumulate all later duplicates (orig p's -> exact merge).
        bool deadA = (e1 && (kA1 == kA || kB1 == kA))
                  || (e2 && (kA2 == kA || kB2 == kA))
                  || (e3 && (kA3 == kA || kB3 == kA));
        float wA = pA + ((kB == kA) ? pB : 0.f)
                 + (!e1 ? ((kA1 == kA ? pA1 : 0.f) + (kB1 == kA ? pB1 : 0.f)) : 0.f)
                 + (!e2 ? ((kA2 == kA ? pA2 : 0.f) + (kB2 == kA ? pB2 : 0.f)) : 0.f)
                 + (!e3 ? ((kA3 == kA ? pA3 : 0.f) + (kB3 == kA ? pB3 : 0.f)) : 0.f);
        // slot B (s = 2q+1): own slot A is earlier.
        bool deadB = (kA == kB)
                  || (e1 && (kA1 == kB || kB1 == kB))
                  || (e2 && (kA2 == kB || kB2 == kB))
                  || (e3 && (kA3 == kB || kB3 == kB));
        float wB = pB
                 + (!e1 ? ((kA1 == kB ? pA1 : 0.f) + (kB1 == kB ? pB1 : 0.f)) : 0.f)
                 + (!e2 ? ((kA2 == kB ? pA2 : 0.f) + (kB2 == kB ? pB2 : 0.f)) : 0.f)
                 + (!e3 ? ((kA3 == kB ? pA3 : 0.f) + (kB3 == kB ? pB3 : 0.f)) : 0.f);

        // predicated gathers (TA/L1, x[b] cache-resident) then LDS atomics
        float xvA = 0.f, xvB = 0.f;
        if (!deadA) xvA = xb[iiA];
        if (!deadB) xvB = xb[iiB];
        if (!deadA) atomicAdd(&ys[oiA], wscale * wA * xvA);
        if (!deadB) atomicAdd(&ys[oiB], wscale * wB * xvB);

        nz = nz_n; mean = mean_n; sigma = sigma_n; value = value_n;
    }
    __syncthreads();

    // one HW fp atomic per output element per block (no CAS loop)
    float* yb = y + (size_t)b * OUT_SIZE;
    #pragma unroll
    for (int o = tid; o < OUT_SIZE; o += BLOCK_THREADS) {
        unsafeAtomicAdd(&yb[o], ys[o]);
    }
}

extern "C" void kernel_launch(void* const* d_in, const int* in_sizes, int n_in,
                              void* d_out, int out_size, void* d_ws, size_t ws_size,
                              hipStream_t stream) {
    const float* x      = (const float*)d_in[0];   // [B, IN_SIZE]
    const float* means  = (const float*)d_in[1];   // [B, N, 2]
    const float* sigmas = (const float*)d_in[2];   // [B, N]
    const float* values = (const float*)d_in[3];   // [B, N]
    const float* bias   = (const float*)d_in[4];   // [OUT_SIZE]
    const float* noise  = (const float*)d_in[5];   // [B, N, D, 2]
    float* y = (float*)d_out;                      // [B, OUT_SIZE]

    init_out<<<(BB * OUT_SIZE) / 256, 256, 0, stream>>>(bias, y);
    hyper_scatter<<<BB * BLOCKS_PER_B, BLOCK_THREADS, 0, stream>>>(
        x, means, sigmas, values, noise, y);
}

// Round 7
// 132.966 us; speedup vs baseline: 1.1194x; 1.1194x over previous
//
#include <hip/hip_runtime.h>
#include <math.h>

// Problem constants (from reference)
#define BB 16
#define NN 65536
#define DD 8
#define OUT_SIZE 4096
#define IN_SIZE 4096

#define BLOCKS_PER_B 32
#define NC (NN / BLOCKS_PER_B)   // 2048 tuples per block
#define BLOCK_THREADS 1024       // 16 waves/block

// y[b,o] = bias[o]  (output is re-poisoned before every timed launch)
__global__ void init_out(const float* __restrict__ bias, float* __restrict__ y) {
    int i = blockIdx.x * blockDim.x + threadIdx.x;     // 0 .. B*OUT_SIZE-1
    y[i] = bias[i & (OUT_SIZE - 1)];
}

__global__ __launch_bounds__(BLOCK_THREADS, 4)
void hyper_scatter(const float* __restrict__ x,
                   const float* __restrict__ means,
                   const float* __restrict__ sigmas,
                   const float* __restrict__ values,
                   const float* __restrict__ noise,
                   float* __restrict__ y) {
    __shared__ float ys[OUT_SIZE];   // per-(b,chunk) partial output, 16 KB
    __shared__ float xs[IN_SIZE];    // staged x[b,:], 16 KB (DS pipe is light now)

    const int b     = blockIdx.x / BLOCKS_PER_B;
    const int chunk = blockIdx.x % BLOCKS_PER_B;
    const int tid   = threadIdx.x;

    // zero partial accumulator + stage x[b] (1024 threads cover 1024 float4s each)
    {
        const float4* xsrc = (const float4*)(x + (size_t)b * IN_SIZE);
        ((float4*)ys)[tid] = make_float4(0.f, 0.f, 0.f, 0.f);
        ((float4*)xs)[tid] = xsrc[tid];
    }
    __syncthreads();

    const int n0 = chunk * NC;
    #pragma unroll
    for (int nl = tid; nl < NC; nl += BLOCK_THREADS) {   // exactly 2 iterations
        const size_t base = (size_t)b * NN + (size_t)(n0 + nl);
        const float2 mean  = ((const float2*)means)[base];
        const float  sigma = sigmas[base];
        const float  value = values[base];

        // noise[b,n,:,:] = 16 contiguous floats, 64B-aligned
        const float4* np4 = (const float4*)(noise + base * (size_t)(DD * 2));
        float4 nz0 = np4[0], nz1 = np4[1], nz2 = np4[2], nz3 = np4[3];
        float nr[DD * 2] = { nz0.x, nz0.y, nz0.z, nz0.w,
                             nz1.x, nz1.y, nz1.z, nz1.w,
                             nz2.x, nz2.y, nz2.z, nz2.w,
                             nz3.x, nz3.y, nz3.z, nz3.w };

        const float neg_inv_2s2 = -0.5f / (sigma * sigma);

        float p[DD];
        int   oi[DD], ii[DD];
        float psum = 0.f;
        #pragma unroll
        for (int d = 0; d < DD; ++d) {
            // EXACT sample rounding: mul-then-add, no FMA contraction,
            // so rintf() flips the same half-integer cases as np.round.
            float s0 = __fadd_rn(__fmul_rn(nr[2 * d],     sigma), mean.x);
            float s1 = __fadd_rn(__fmul_rn(nr[2 * d + 1], sigma), mean.y);
            float d0 = s0 - mean.x;             // reference's diff (post-roundtrip)
            float d1 = s1 - mean.y;
            float q  = d0 * d0 + d1 * d1;
            float pd = __expf(q * neg_inv_2s2); // 1/(2πσ²) cancels in normalization
            p[d] = pd;
            psum += pd;
            oi[d] = (int)fminf(fmaxf(rintf(s0), 0.f), (float)(OUT_SIZE - 1));
            ii[d] = (int)fminf(fmaxf(rintf(s1), 0.f), (float)(IN_SIZE - 1));
        }
        const float wscale = value / psum;      // one divide per tuple

        // ---- level 1: dedupe on full (oi,ii) key (merge p-weights).
        // "Accumulate each later duplicate into all earlier matches": the
        // first slot of each key receives the exact sum; polluted later
        // slots are dead (dupP) and never used (their xv is forced to 0).
        int   key[DD];
        float w[DD];
        #pragma unroll
        for (int d = 0; d < DD; ++d) { key[d] = (oi[d] << 12) | ii[d]; w[d] = p[d]; }
        #pragma unroll
        for (int d = 1; d < DD; ++d) {
            #pragma unroll
            for (int j = 0; j < d; ++j) {
                if (key[j] == key[d]) w[j] += w[d];   // cndmask-add, no branch
            }
        }
        bool dupP[DD];
        #pragma unroll
        for (int d = 0; d < DD; ++d) {
            bool dd = false;
            #pragma unroll
            for (int j = 0; j < d; ++j) dd = dd || (key[j] == key[d]);
            dupP[d] = dd;
        }

        // ---- gathers from LDS (predicated: masked lanes touch no banks)
        float v[DD];
        #pragma unroll
        for (int d = 0; d < DD; ++d) {
            float xv = 0.f;
            if (!dupP[d]) xv = xs[ii[d]];
            v[d] = w[d] * xv;                   // dupP slots: v = 0
        }

        // ---- level 2: merge w*x products on oi alone (atomic-lane dedupe).
        // Invariant: for each oi value, the FIRST slot holding it is
        // !dupP && !deadO — the unique live receiver. deadO[j] (j<d) is
        // final before iteration d, so each product is added exactly once.
        bool deadO[DD];
        deadO[0] = false;
        #pragma unroll
        for (int d = 1; d < DD; ++d) {
            bool found = false;
            #pragma unroll
            for (int j = 0; j < d; ++j) {
                bool m = (!dupP[j]) && (!deadO[j]) && (oi[j] == oi[d]);
                if (m) v[j] += v[d];
                found = found || m;
            }
            deadO[d] = found;
        }

        // ---- scatter: one LDS atomic per UNIQUE oi (~4.8 of 8)
        #pragma unroll
        for (int d = 0; d < DD; ++d) {
            if (!dupP[d] && !deadO[d]) atomicAdd(&ys[oi[d]], wscale * v[d]);
        }
    }
    __syncthreads();

    // one HW fp atomic per output element per block (coalesced, cheap)
    float* yb = y + (size_t)b * OUT_SIZE;
    #pragma unroll
    for (int o = tid; o < OUT_SIZE; o += BLOCK_THREADS) {
        unsafeAtomicAdd(&yb[o], ys[o]);
    }
}

extern "C" void kernel_launch(void* const* d_in, const int* in_sizes, int n_in,
                              void* d_out, int out_size, void* d_ws, size_t ws_size,
                              hipStream_t stream) {
    const float* x      = (const float*)d_in[0];   // [B, IN_SIZE]
    const float* means  = (const float*)d_in[1];   // [B, N, 2]
    const float* sigmas = (const float*)d_in[2];   // [B, N]
    const float* values = (const float*)d_in[3];   // [B, N]
    const float* bias   = (const float*)d_in[4];   // [OUT_SIZE]
    const float* noise  = (const float*)d_in[5];   // [B, N, D, 2]
    float* y = (float*)d_out;                      // [B, OUT_SIZE]

    init_out<<<(BB * OUT_SIZE) / 256, 256, 0, stream>>>(bias, y);
    hyper_scatter<<<BB * BLOCKS_PER_B, BLOCK_THREADS, 0, stream>>>(
        x, means, sigmas, values, noise, y);
}

// Round 8
// 130.778 us; speedup vs baseline: 1.1381x; 1.0167x over previous
//
#include <hip/hip_runtime.h>
#include <math.h>

// Problem constants (from reference)
#define BB 16
#define NN 65536
#define DD 8
#define OUT_SIZE 4096
#define IN_SIZE 4096

#define BLOCKS_PER_B 32
#define NC (NN / BLOCKS_PER_B)   // 2048 tuples per block
#define BLOCK_THREADS 1024       // 16 waves/block

// y[b,o] = bias[o]  (output is re-poisoned before every timed launch)
__global__ void init_out(const float* __restrict__ bias, float* __restrict__ y) {
    int i = blockIdx.x * blockDim.x + threadIdx.x;     // 0 .. B*OUT_SIZE-1
    y[i] = bias[i & (OUT_SIZE - 1)];
}

__global__ __launch_bounds__(BLOCK_THREADS, 4)
void hyper_scatter(const float* __restrict__ x,
                   const float* __restrict__ means,
                   const float* __restrict__ sigmas,
                   const float* __restrict__ values,
                   const float* __restrict__ noise,
                   float* __restrict__ y) {
    __shared__ float ys[OUT_SIZE];   // per-(b,chunk) partial output, 16 KB
    __shared__ float xs[IN_SIZE];    // staged x[b,:], 16 KB

    const int b     = blockIdx.x / BLOCKS_PER_B;
    const int chunk = blockIdx.x % BLOCKS_PER_B;
    const int tid   = threadIdx.x;
    const float* xb = x + (size_t)b * IN_SIZE;

    // zero partial accumulator + stage x[b] (1024 threads, 1 float4 each)
    ((float4*)ys)[tid] = make_float4(0.f, 0.f, 0.f, 0.f);
    ((float4*)xs)[tid] = ((const float4*)xb)[tid];
    __syncthreads();

    const int n0 = chunk * NC;
    #pragma unroll
    for (int nl = tid; nl < NC; nl += BLOCK_THREADS) {   // exactly 2 iterations
        const size_t base = (size_t)b * NN + (size_t)(n0 + nl);
        const float2 mean  = ((const float2*)means)[base];
        const float  sigma = sigmas[base];
        const float  value = values[base];

        // noise[b,n,:,:] = 16 contiguous floats, 64B-aligned
        const float4* np4 = (const float4*)(noise + base * (size_t)(DD * 2));
        float4 nz0 = np4[0], nz1 = np4[1], nz2 = np4[2], nz3 = np4[3];
        float nr[DD * 2] = { nz0.x, nz0.y, nz0.z, nz0.w,
                             nz1.x, nz1.y, nz1.z, nz1.w,
                             nz2.x, nz2.y, nz2.z, nz2.w,
                             nz3.x, nz3.y, nz3.z, nz3.w };

        const float neg_inv_2s2 = -0.5f / (sigma * sigma);

        float p[DD];
        int   oi[DD], ii[DD];
        float psum = 0.f;
        #pragma unroll
        for (int d = 0; d < DD; ++d) {
            // EXACT sample rounding: mul-then-add, no FMA contraction,
            // so rintf() flips the same half-integer cases as np.round.
            float s0 = __fadd_rn(__fmul_rn(nr[2 * d],     sigma), mean.x);
            float s1 = __fadd_rn(__fmul_rn(nr[2 * d + 1], sigma), mean.y);
            float d0 = s0 - mean.x;             // reference's diff (post-roundtrip)
            float d1 = s1 - mean.y;
            float q  = d0 * d0 + d1 * d1;
            float pd = __expf(q * neg_inv_2s2); // 1/(2πσ²) cancels in normalization
            p[d] = pd;
            psum += pd;
            oi[d] = (int)fminf(fmaxf(rintf(s0), 0.f), (float)(OUT_SIZE - 1));
            ii[d] = (int)fminf(fmaxf(rintf(s1), 0.f), (float)(IN_SIZE - 1));
        }
        const float wscale = value / psum;      // one divide per tuple

        // ---- gather-dedupe on ii alone (~4.8 unique of 8):
        // only the FIRST slot holding each ii issues a load; later slots
        // inherit via triangular cndmask propagation (unique donor each).
        bool dupI[DD];
        #pragma unroll
        for (int d = 0; d < DD; ++d) {
            bool dd = false;
            #pragma unroll
            for (int j = 0; j < d; ++j) dd = dd || (ii[j] == ii[d]);
            dupI[d] = dd;
        }
        // predicated loads, pipe-split: even slots -> LDS (DS pipe),
        // odd slots -> global x[b] (TA/L1 pipe, cache-resident 16 KB).
        float xv[DD];
        #pragma unroll
        for (int d = 0; d < DD; ++d) {
            xv[d] = 0.f;
            if (!dupI[d]) xv[d] = (d & 1) ? xb[ii[d]] : xs[ii[d]];
        }
        // propagate to duplicate slots (donor j is the unique !dupI match)
        #pragma unroll
        for (int d = 1; d < DD; ++d) {
            #pragma unroll
            for (int j = 0; j < d; ++j) {
                if (!dupI[j] && ii[j] == ii[d]) xv[d] = xv[j];
            }
        }

        // products (all 8 slots live)
        float v[DD];
        #pragma unroll
        for (int d = 0; d < DD; ++d) v[d] = p[d] * xv[d];

        // ---- merge products on oi (~4.8 unique of 8): first slot per oi
        // is the unique live receiver; deadO[j] is final before iter d.
        bool deadO[DD];
        deadO[0] = false;
        #pragma unroll
        for (int d = 1; d < DD; ++d) {
            bool found = false;
            #pragma unroll
            for (int j = 0; j < d; ++j) {
                bool m = (!deadO[j]) && (oi[j] == oi[d]);
                if (m) v[j] += v[d];
                found = found || m;
            }
            deadO[d] = found;
        }

        // ---- scatter: one LDS atomic per UNIQUE oi
        #pragma unroll
        for (int d = 0; d < DD; ++d) {
            if (!deadO[d]) atomicAdd(&ys[oi[d]], wscale * v[d]);
        }
    }
    __syncthreads();

    // one HW fp atomic per output element per block (coalesced, cheap)
    float* yb = y + (size_t)b * OUT_SIZE;
    #pragma unroll
    for (int o = tid; o < OUT_SIZE; o += BLOCK_THREADS) {
        unsafeAtomicAdd(&yb[o], ys[o]);
    }
}

extern "C" void kernel_launch(void* const* d_in, const int* in_sizes, int n_in,
                              void* d_out, int out_size, void* d_ws, size_t ws_size,
                              hipStream_t stream) {
    const float* x      = (const float*)d_in[0];   // [B, IN_SIZE]
    const float* means  = (const float*)d_in[1];   // [B, N, 2]
    const float* sigmas = (const float*)d_in[2];   // [B, N]
    const float* values = (const float*)d_in[3];   // [B, N]
    const float* bias   = (const float*)d_in[4];   // [OUT_SIZE]
    const float* noise  = (const float*)d_in[5];   // [B, N, D, 2]
    float* y = (float*)d_out;                      // [B, OUT_SIZE]

    init_out<<<(BB * OUT_SIZE) / 256, 256, 0, stream>>>(bias, y);
    hyper_scatter<<<BB * BLOCKS_PER_B, BLOCK_THREADS, 0, stream>>>(
        x, means, sigmas, values, noise, y);
}